// Round 4
// baseline (25117.149 us; speedup 1.0000x reference)
//
#include <hip/hip_runtime.h>
#include <hip/hip_bf16.h>

// Problem constants (S,B,D,H,T) = (4,512,256,1024,50)
#define S_ 4
#define B_ 512
#define D_ 256
#define H_ 1024
#define T_ 50
#define M_ (S_*B_)   // 2048 rows total

typedef __attribute__((ext_vector_type(8))) __bf16 bf16x8;
typedef __attribute__((ext_vector_type(4))) float  f32x4;
typedef __attribute__((ext_vector_type(8))) unsigned short u16x8;

// NaN-free fast tanh: saturates to +/-1, ~1e-6 abs error (<< bf16 eps)
__device__ __forceinline__ float fast_tanh(float x) {
  const float e = __expf(2.f * x);
  return 1.f - 2.f / (e + 1.f);
}

// ---------------------------------------------------------------------------
// Runtime dtype detection + dt table (verified in rounds 2-3).
//   flags[0] = weights/first_point/output are f32 (1) or bf16 (0)
//   flags[1] = time grid is f32 (1) or bf16 (0)
// ---------------------------------------------------------------------------
__global__ void detect_k(const void* t_raw, const void* w2_raw,
                         float* dts, int* flags) {
  __shared__ int cnt;
  const int l = threadIdx.x;           // 64 threads, 1 block
  if (l == 0) cnt = 0;
  __syncthreads();
  const unsigned short* u = (const unsigned short*)w2_raw;
  int c = 0;
  #pragma unroll
  for (int j = 0; j < 4; ++j) {
    const unsigned short v = u[l * 4 + j];
    const unsigned e = (v >> 7) & 0xFF;          // bf16 exponent field
    if (e >= 128) c++;                            // |x| >= 2.0 or NaN/Inf
  }
  atomicAdd(&cnt, c);
  __syncthreads();
  const unsigned tw0 = *(const unsigned*)t_raw;
  const int t_is_f32 = (tw0 == 0u) ? 1 : 0;
  const int w_is_f32 = (cnt > 16) ? 1 : 0;
  if (l == 0) { flags[0] = w_is_f32; flags[1] = t_is_f32; }
  if (l < T_ - 1) {
    float t0, t1;
    if (t_is_f32) {
      const float* tf = (const float*)t_raw;
      t0 = tf[l]; t1 = tf[l + 1];
    } else {
      const __hip_bfloat16* tb = (const __hip_bfloat16*)t_raw;
      t0 = __bfloat162float(tb[l]); t1 = __bfloat162float(tb[l + 1]);
    }
    dts[l] = t1 - t0;
  }
}

// ---------------------------------------------------------------------------
// Pack weight W[K][N] (row-major, dtype per flags[0]) into fragment-major
// bf16 chunks: chunk c = ((ntile*(K/32) + ktile)*64 + lane), holding 8 elems
//   dst[c*8 + j] = W[ktile*32 + (lane>>4)*8 + j][ntile*16 + (lane&15)]
// so each wave B-fragment load is one contiguous 1 KB global_load_dwordx4.
// ---------------------------------------------------------------------------
__global__ void pack_w_k(const void* __restrict__ src,
                         __hip_bfloat16* __restrict__ dst,
                         int K, int N, const int* __restrict__ flags) {
  const int f32 = flags[0];
  const int c = blockIdx.x * 256 + threadIdx.x;   // total K*N/8 chunks
  const int lane = c & 63;
  const int rem = c >> 6;
  const int KT = K >> 5;
  const int kt = rem % KT;
  const int nt = rem / KT;
  const int n = nt * 16 + (lane & 15);
  const int kb = kt * 32 + (lane >> 4) * 8;
  u16x8 v;
  #pragma unroll
  for (int j = 0; j < 8; ++j) {
    const size_t si = (size_t)(kb + j) * N + n;
    const __hip_bfloat16 b = f32 ? __float2bfloat16(((const float*)src)[si])
                                 : ((const __hip_bfloat16*)src)[si];
    v[j] = __builtin_bit_cast(unsigned short, b);
  }
  *(u16x8*)&dst[(size_t)c * 8] = v;
}

// ---------------------------------------------------------------------------
// biases -> fp32 workspace arrays; also zero reg_state tail of out
// ---------------------------------------------------------------------------
__global__ void prep_bias_k(const void* b1r, const void* b2r, const void* b3r,
                            float* bf1, float* bf2, float* bf3,
                            void* out, const int* flags) {
  const int i = blockIdx.x * 256 + threadIdx.x;   // H_ threads
  const int f32 = flags[0];
  bf1[i] = f32 ? ((const float*)b1r)[i]
               : __bfloat162float(((const __hip_bfloat16*)b1r)[i]);
  bf2[i] = f32 ? ((const float*)b2r)[i]
               : __bfloat162float(((const __hip_bfloat16*)b2r)[i]);
  if (i < D_)
    bf3[i] = f32 ? ((const float*)b3r)[i]
                 : __bfloat162float(((const __hip_bfloat16*)b3r)[i]);
  if (i < S_) {
    const size_t ro = (size_t)M_ * T_ * D_ + i;
    if (f32) ((float*)out)[ro] = 0.f;
    else     ((__hip_bfloat16*)out)[ro] = __float2bfloat16(0.f);
  }
}

// ---------------------------------------------------------------------------
// Software-pipelined layer core. Wlane = packed base + wave/lane offset.
// Loads for k-tile kt+DEPTH are issued after the MFMAs of kt -> DEPTH k-tiles
// of L2 latency hiding, no barrier inside the loop (compiler emits partial
// vmcnt, never vmcnt(0)).
// ---------------------------------------------------------------------------
template <int K, int NT, int DEPTH>
__device__ __forceinline__ void layer_mfma(
    const __hip_bfloat16* __restrict__ Wlane,
    const __hip_bfloat16* __restrict__ Ab, int astr,
    int l16, int quad, f32x4* acc) {
  constexpr int KT = K / 32;
  const __hip_bfloat16* arow = Ab + l16 * astr + quad * 8;
  bf16x8 buf[DEPTH][NT];
  #pragma unroll
  for (int d = 0; d < DEPTH; ++d)
    #pragma unroll
    for (int ni = 0; ni < NT; ++ni)
      buf[d][ni] = *(const bf16x8*)&Wlane[(ni * KT + d) * 512];
  #pragma unroll
  for (int kt = 0; kt < KT; ++kt) {
    const bf16x8 aF = *(const bf16x8*)&arow[kt * 32];
    #pragma unroll
    for (int ni = 0; ni < NT; ++ni)
      acc[ni] = __builtin_amdgcn_mfma_f32_16x16x32_bf16(
          aF, buf[kt % DEPTH][ni], acc[ni], 0, 0, 0);
    if (kt + DEPTH < KT) {
      #pragma unroll
      for (int ni = 0; ni < NT; ++ni)
        buf[kt % DEPTH][ni] =
            *(const bf16x8*)&Wlane[(ni * KT + kt + DEPTH) * 512];
    }
  }
}

// ---------------------------------------------------------------------------
// Persistent RK4 integrator. 128 blocks x 1024 threads (16 waves, 4/SIMD).
// Block owns 16 rows for all 49 steps; weights stream from per-XCD L2 as
// packed fragments (contiguous 1 KB per load), double-buffered in registers.
// Wave w owns N-cols [w*64, w*64+64) in L1/L2 and [w*16, w*16+16) in L3.
// MFMA (verified r2/r3): A[m=l16][k=quad*8+j], B[n=l16][k=quad*8+j],
// C: col=l16, row=quad*4+reg.
// ---------------------------------------------------------------------------
__global__ __launch_bounds__(1024, 4) void ode_persist(
    const void* __restrict__ fp_raw, void* __restrict__ out,
    const __hip_bfloat16* __restrict__ W1p,
    const __hip_bfloat16* __restrict__ W2p,
    const __hip_bfloat16* __restrict__ W3p,
    const float* __restrict__ bf1, const float* __restrict__ bf2,
    const float* __restrict__ bf3,
    const float* __restrict__ dts, const int* __restrict__ flags) {
  // LDS: 3*16K (fp32 state) + 8448 (u) + 2*33024 (h1,h2) = 123648 B
  __shared__ float y[16 * 256];
  __shared__ float kcur[16 * 256];
  __shared__ float kacc[16 * 256];
  __shared__ __hip_bfloat16 ubuf[16 * 264];   // row stride 264
  __shared__ __hip_bfloat16 h1[16 * 1032];    // row stride 1032
  __shared__ __hip_bfloat16 h2[16 * 1032];

  const int tid = threadIdx.x;
  const int wave = tid >> 6, lane = tid & 63;
  const int quad = lane >> 4, l16 = lane & 15;
  const int m0 = blockIdx.x * 16;
  const int ofl = flags[0];

  // per-wave/lane packed-weight bases
  const __hip_bfloat16* W1l = W1p + (size_t)wave * 4 * 8  * 512 + lane * 8;
  const __hip_bfloat16* W2l = W2p + (size_t)wave * 4 * 32 * 512 + lane * 8;
  const __hip_bfloat16* W3l = W3p + (size_t)wave * 32 * 512 + lane * 8;

  // ---- prologue: load y rows, write t=0 traj, zero k ----
  for (int i = tid; i < 16 * 256; i += 1024) {
    const int r = i >> 8, c = i & 255;
    const size_t gi = (size_t)(m0 + r) * 256 + c;
    const float v = ofl ? ((const float*)fp_raw)[gi]
                        : __bfloat162float(((const __hip_bfloat16*)fp_raw)[gi]);
    y[i] = v; kcur[i] = 0.f; kacc[i] = 0.f;
    const size_t o = (size_t)((m0 + r) * T_) * D_ + c;
    if (ofl) __builtin_nontemporal_store(v, &((float*)out)[o]);
    else     ((__hip_bfloat16*)out)[o] = __float2bfloat16(v);
  }
  // biases into registers
  float bia1[4], bia2[4];
  #pragma unroll
  for (int ni = 0; ni < 4; ni++) {
    bia1[ni] = bf1[wave * 64 + ni * 16 + l16];
    bia2[ni] = bf2[wave * 64 + ni * 16 + l16];
  }
  const float bia3 = bf3[wave * 16 + l16];
  __syncthreads();

  #pragma unroll 1
  for (int st = 0; st < T_ - 1; ++st) {
    const float dtv = dts[st];
    #pragma unroll 1
    for (int stage = 0; stage < 4; ++stage) {
      const float cc = (stage == 0) ? 0.f : ((stage == 3) ? 1.f : 0.5f);
      const float cdt = cc * dtv;

      // ---- build u = bf16(y + cdt*k_prev): 4 elems/thread ----
      {
        const int i0 = tid * 4;                 // 4096 elems / 1024 threads
        const int row = i0 >> 8, col = i0 & 255;
        const float4 yv = *(const float4*)&y[i0];
        const float4 kv = *(const float4*)&kcur[i0];
        ushort4 pk;
        pk.x = __builtin_bit_cast(unsigned short, __float2bfloat16(yv.x + cdt * kv.x));
        pk.y = __builtin_bit_cast(unsigned short, __float2bfloat16(yv.y + cdt * kv.y));
        pk.z = __builtin_bit_cast(unsigned short, __float2bfloat16(yv.z + cdt * kv.z));
        pk.w = __builtin_bit_cast(unsigned short, __float2bfloat16(yv.w + cdt * kv.w));
        *(ushort4*)&ubuf[row * 264 + col] = pk;
      }
      __syncthreads();

      // ---- L1: h1 = tanh(u @ W1 + b1), K=256, 4 n-tiles/wave ----
      {
        f32x4 acc[4];
        #pragma unroll
        for (int ni = 0; ni < 4; ni++) acc[ni] = f32x4{0.f, 0.f, 0.f, 0.f};
        layer_mfma<256, 4, 2>(W1l, ubuf, 264, l16, quad, acc);
        #pragma unroll
        for (int ni = 0; ni < 4; ni++) {
          const int gn = wave * 64 + ni * 16 + l16;
          #pragma unroll
          for (int r = 0; r < 4; r++)
            h1[(quad * 4 + r) * 1032 + gn] =
                __float2bfloat16(fast_tanh(acc[ni][r] + bia1[ni]));
        }
      }
      __syncthreads();

      // ---- L2: h2 = tanh(h1 @ W2 + b2), K=1024, 4 n-tiles/wave ----
      {
        f32x4 acc[4];
        #pragma unroll
        for (int ni = 0; ni < 4; ni++) acc[ni] = f32x4{0.f, 0.f, 0.f, 0.f};
        layer_mfma<1024, 4, 2>(W2l, h1, 1032, l16, quad, acc);
        #pragma unroll
        for (int ni = 0; ni < 4; ni++) {
          const int gn = wave * 64 + ni * 16 + l16;
          #pragma unroll
          for (int r = 0; r < 4; r++)
            h2[(quad * 4 + r) * 1032 + gn] =
                __float2bfloat16(fast_tanh(acc[ni][r] + bia2[ni]));
        }
      }
      __syncthreads();

      // ---- L3: k = h2 @ W3 + b3, K=1024, 1 n-tile/wave + RK4 update ----
      {
        f32x4 acc3[1];
        acc3[0] = f32x4{0.f, 0.f, 0.f, 0.f};
        layer_mfma<1024, 1, 4>(W3l, h2, 1032, l16, quad, acc3);
        const int col = wave * 16 + l16;
        #pragma unroll
        for (int r = 0; r < 4; r++) {
          const int row = quad * 4 + r;
          const int idx = row * 256 + col;
          const float v = acc3[0][r] + bia3;
          if (stage < 3) {
            kcur[idx] = v;
            kacc[idx] = (stage == 0) ? v : kacc[idx] + 2.f * v;
          } else {
            const float yv = y[idx] + (dtv * (1.f / 6.f)) * (kacc[idx] + v);
            y[idx] = yv;
            const size_t o = (size_t)((m0 + row) * T_ + st + 1) * D_ + col;
            if (ofl) __builtin_nontemporal_store(yv, &((float*)out)[o]);
            else     ((__hip_bfloat16*)out)[o] = __float2bfloat16(yv);
          }
        }
      }
      __syncthreads();
    }
  }
}

// ---------------------------------------------------------------------------
extern "C" void kernel_launch(void* const* d_in, const int* in_sizes, int n_in,
                              void* d_out, int out_size, void* d_ws, size_t ws_size,
                              hipStream_t stream) {
  const void* fp   = d_in[0];
  const void* tarr = d_in[1];
  const void* W1   = d_in[2];
  const void* b1   = d_in[3];
  const void* W2   = d_in[4];
  const void* b2   = d_in[5];
  const void* W3   = d_in[6];
  const void* b3   = d_in[7];

  // workspace carve (~3.2 MB)
  char* ws = (char*)d_ws;
  float* bf1  = (float*)ws;                  ws += (size_t)H_ * 4;
  float* bf2  = (float*)ws;                  ws += (size_t)H_ * 4;
  float* bf3  = (float*)ws;                  ws += (size_t)D_ * 4;
  float* dts  = (float*)ws;                  ws += 64 * 4;
  int*   flags= (int*)ws;                    ws += 64 * 4;
  __hip_bfloat16* W1p = (__hip_bfloat16*)ws; ws += (size_t)H_ * D_ * 2;
  __hip_bfloat16* W2p = (__hip_bfloat16*)ws; ws += (size_t)H_ * H_ * 2;
  __hip_bfloat16* W3p = (__hip_bfloat16*)ws; ws += (size_t)D_ * H_ * 2;

  detect_k<<<1, 64, 0, stream>>>(tarr, W2, dts, flags);
  pack_w_k<<<(D_ * H_ / 8) / 256, 256, 0, stream>>>(W1, W1p, D_, H_, flags);
  pack_w_k<<<(H_ * H_ / 8) / 256, 256, 0, stream>>>(W2, W2p, H_, H_, flags);
  pack_w_k<<<(H_ * D_ / 8) / 256, 256, 0, stream>>>(W3, W3p, H_, D_, flags);
  prep_bias_k<<<H_ / 256, 256, 0, stream>>>(b1, b2, b3, bf1, bf2, bf3, d_out, flags);

  ode_persist<<<M_ / 16, 1024, 0, stream>>>(fp, d_out, W1p, W2p, W3p,
                                            bf1, bf2, bf3, dts, flags);
}